// Round 1
// baseline (706.122 us; speedup 1.0000x reference)
//
#include <hip/hip_runtime.h>

#define B_  2
#define S_  2048
#define D_  512
#define H_  8
#define E_  512
#define HE_ 4096

typedef _Float16 half8_t  __attribute__((ext_vector_type(8)));
typedef _Float16 half4_t  __attribute__((ext_vector_type(4)));
typedef float    floatx4  __attribute__((ext_vector_type(4)));

// ---------------- cast fp32 -> fp16 (vectorized) ----------------
__global__ __launch_bounds__(256) void cast_f16_kernel(const float* __restrict__ src,
                                                       _Float16* __restrict__ dst, int n4) {
    int i = blockIdx.x * 256 + threadIdx.x;
    if (i >= n4) return;
    float4 v = ((const float4*)src)[i];
    half4_t h = { (_Float16)v.x, (_Float16)v.y, (_Float16)v.z, (_Float16)v.w };
    ((half4_t*)dst)[i] = h;
}

// ------------- transpose + cast: src fp32 [R,C] -> dst fp16 [C,R], batched -------------
__global__ __launch_bounds__(256) void transpose_cast_kernel(const float* __restrict__ src,
                                                             _Float16* __restrict__ dst,
                                                             int R, int C) {
    __shared__ float t[32][33];
    long long zoff = (long long)blockIdx.z * R * C;
    src += zoff; dst += zoff;
    int c0 = blockIdx.x * 32, r0 = blockIdx.y * 32;
    int tx = threadIdx.x, ty = threadIdx.y;
#pragma unroll
    for (int i = 0; i < 32; i += 8)
        t[ty + i][tx] = src[(long long)(r0 + ty + i) * C + (c0 + tx)];
    __syncthreads();
#pragma unroll
    for (int i = 0; i < 32; i += 8)
        dst[(long long)(c0 + ty + i) * R + (r0 + tx)] = (_Float16)t[tx][ty + i];
}

// ------------- bt-GEMM: C[M,N] = A[M,K] * Bt[N,K]^T (+bias[n]), fp16 in, fp32 acc -------------
// Tile 64x64, 256 threads (4 waves in 2x2), K-chunk 32 = one mfma_f32_16x16x32_f16 step.
// Fragment layouts (guide §3, verified m89/m91/m121):
//   A/B operand: elem [m|n = lane&15][k = (lane>>4)*8 + j], j=0..7  (8 contiguous fp16 = 16B)
//   C/D: col = lane&15, row = (lane>>4)*4 + reg
__global__ __launch_bounds__(256) void gemm_bt_kernel(
    const _Float16* __restrict__ A, const _Float16* __restrict__ Bt,
    const float* __restrict__ bias, void* __restrict__ C, int out_f32,
    int K, int lda, int ldb,
    long long a_b, long long a_h, long long b_b, long long b_h,
    long long c_b, long long c_h, int c_rs, int c_cs,
    int divh, int bias_h)
{
    int z  = blockIdx.z;
    int bb = z / divh, hh = z % divh;
    A  += bb * a_b + hh * a_h;
    Bt += bb * b_b + hh * b_h;
    long long coff = bb * c_b + hh * c_h;

    int m0 = blockIdx.y * 64;
    int n0 = blockIdx.x * 64;

    // +8 fp16 pad -> 80B row stride (16B-aligned, breaks pow2 bank stride)
    __shared__ __align__(16) _Float16 As[64][40];
    __shared__ __align__(16) _Float16 Bs[64][40];

    int tid  = threadIdx.x;
    int wave = tid >> 6, lane = tid & 63;
    int quad = lane >> 4, l16 = lane & 15;
    int wy = (wave >> 1) * 32, wx = (wave & 1) * 32;

    int sr = tid >> 2;        // 0..63 staging row
    int sc = (tid & 3) * 8;   // staging col (fp16 elems)

    floatx4 acc[2][2] = {};

    for (int k0 = 0; k0 < K; k0 += 32) {
        int4 av = *(const int4*)(A  + (long long)(m0 + sr) * lda + k0 + sc);
        int4 bv = *(const int4*)(Bt + (long long)(n0 + sr) * ldb + k0 + sc);
        if (k0) __syncthreads();
        *(int4*)&As[sr][sc] = av;
        *(int4*)&Bs[sr][sc] = bv;
        __syncthreads();
#pragma unroll
        for (int mi = 0; mi < 2; mi++) {
            half8_t af = *(const half8_t*)&As[wy + mi * 16 + l16][quad * 8];
#pragma unroll
            for (int ni = 0; ni < 2; ni++) {
                half8_t bf = *(const half8_t*)&Bs[wx + ni * 16 + l16][quad * 8];
                acc[mi][ni] = __builtin_amdgcn_mfma_f32_16x16x32_f16(af, bf, acc[mi][ni], 0, 0, 0);
            }
        }
    }

    float*    fC = (float*)C;
    _Float16* hC = (_Float16*)C;
#pragma unroll
    for (int mi = 0; mi < 2; mi++)
#pragma unroll
        for (int ni = 0; ni < 2; ni++)
#pragma unroll
            for (int r = 0; r < 4; r++) {
                int row = m0 + wy + mi * 16 + quad * 4 + r;
                int col = n0 + wx + ni * 16 + l16;
                float v = acc[mi][ni][r];
                if (bias) v += bias[hh * bias_h + col];
                long long addr = coff + (long long)row * c_rs + (long long)col * c_cs;
                if (out_f32) fC[addr] = v; else hC[addr] = (_Float16)v;
            }
}

// ------------- masked softmax over one row of fp16 scores (in place) -------------
// grid: (S rows, 1, Z); block 256; each thread owns 8 strided elements (S=2048).
__global__ __launch_bounds__(256) void softmax_mask_kernel(_Float16* __restrict__ sc,
                                                           const int* __restrict__ mask,
                                                           long long sc_z, int hdiv, int S)
{
    long long z = blockIdx.z;
    int s = blockIdx.x;
    _Float16* row = sc + z * sc_z + (long long)s * S;
    const int* mrow = mask + (z / hdiv) * (long long)S * S + (long long)s * S;
    int tid = threadIdx.x;

    float v[8];
    float mx = -3.0e38f;
#pragma unroll
    for (int j = 0; j < 8; j++) {
        int c = tid + j * 256;
        float val = (float)row[c];
        val = mrow[c] ? val : -1.0e9f;   // masked_fill(mask==0, -1e9)
        v[j] = val;
        mx = fmaxf(mx, val);
    }
    __shared__ float red[4];
    for (int o = 32; o > 0; o >>= 1) mx = fmaxf(mx, __shfl_xor(mx, o));
    int wave = tid >> 6, lane = tid & 63;
    if (lane == 0) red[wave] = mx;
    __syncthreads();
    mx = fmaxf(fmaxf(red[0], red[1]), fmaxf(red[2], red[3]));

    float sum = 0.0f;
#pragma unroll
    for (int j = 0; j < 8; j++) { v[j] = __expf(v[j] - mx); sum += v[j]; }
    for (int o = 32; o > 0; o >>= 1) sum += __shfl_xor(sum, o);
    __syncthreads();                 // red reuse
    if (lane == 0) red[wave] = sum;
    __syncthreads();
    sum = red[0] + red[1] + red[2] + red[3];
    float inv = 1.0f / sum;
#pragma unroll
    for (int j = 0; j < 8; j++) {
        int c = tid + j * 256;
        row[c] = (_Float16)(v[j] * inv);
    }
}

extern "C" void kernel_launch(void* const* d_in, const int* in_sizes, int n_in,
                              void* d_out, int out_size, void* d_ws, size_t ws_size,
                              hipStream_t stream)
{
    const float* qin = (const float*)d_in[0];
    const float* kin = (const float*)d_in[1];
    const float* vin = (const float*)d_in[2];
    const int*   mask = (const int*)d_in[3];
    const float* Wq = (const float*)d_in[4];
    const float* bq = (const float*)d_in[5];
    const float* Wk = (const float*)d_in[6];
    const float* bk = (const float*)d_in[7];
    const float* Wv = (const float*)d_in[8];
    const float* bv = (const float*)d_in[9];
    const float* Wo = (const float*)d_in[10];
    const float* bo = (const float*)d_in[11];
    float* out = (float*)d_out;

    char* ws = (char*)d_ws;
    size_t off = 0;
    _Float16* WoT = (_Float16*)(ws + off); off += (size_t)E_ * HE_ * 2;           // 4 MiB
    _Float16* Qb  = (_Float16*)(ws + off); off += (size_t)B_ * H_ * S_ * E_ * 2;  // 32 MiB
    _Float16* Kb  = (_Float16*)(ws + off); off += (size_t)B_ * H_ * S_ * E_ * 2;  // 32 MiB
    _Float16* VT  = (_Float16*)(ws + off); off += (size_t)B_ * H_ * E_ * S_ * 2;  // 32 MiB
    size_t region = off;
    // early-scratch (dead after projection GEMMs) — scores region overlays it
    _Float16* Xq  = (_Float16*)(ws + region);
    _Float16* Xk  = Xq  + (size_t)B_ * S_ * D_;
    _Float16* Xv  = Xk  + (size_t)B_ * S_ * D_;
    _Float16* WqT = Xv  + (size_t)B_ * S_ * D_;
    _Float16* WkT = WqT + (size_t)H_ * E_ * D_;
    _Float16* WvT = WkT + (size_t)H_ * E_ * D_;
    _Float16* SC  = (_Float16*)(ws + region);   // fp16 scores / P (in place)
    _Float16* cat = Qb;                          // aliases Q (dead after scores GEMM)

    size_t needPar = region + (size_t)B_ * H_ * S_ * S_ * 2;  // ~228 MiB
    int par = (ws_size >= needPar);

    long long SE = (long long)S_ * E_;
    long long SS = (long long)S_ * S_;
    long long ES = (long long)E_ * S_;
    long long SD = (long long)S_ * D_;
    long long ED = (long long)E_ * D_;

    auto gemm = [&](const _Float16* A, const _Float16* Bt, const float* bias,
                    void* C, int f32, int M, int N, int K, int lda, int ldb,
                    long long ab, long long ah, long long bb2, long long bh,
                    long long cb, long long ch, int rs, int cs,
                    int divh, int biash, int nz) {
        gemm_bt_kernel<<<dim3(N / 64, M / 64, nz), 256, 0, stream>>>(
            A, Bt, bias, C, f32, K, lda, ldb, ab, ah, bb2, bh, cb, ch, rs, cs, divh, biash);
    };

    // 1) cast inputs to fp16
    int n4 = B_ * S_ * D_ / 4;
    cast_f16_kernel<<<dim3(n4 / 256), 256, 0, stream>>>(qin, Xq, n4);
    cast_f16_kernel<<<dim3(n4 / 256), 256, 0, stream>>>(kin, Xk, n4);
    cast_f16_kernel<<<dim3(n4 / 256), 256, 0, stream>>>(vin, Xv, n4);

    // 2) transpose+cast weights to Bt form
    dim3 tb(32, 8);
    transpose_cast_kernel<<<dim3(E_ / 32, D_ / 32, H_), tb, 0, stream>>>(Wq, WqT, D_, E_);
    transpose_cast_kernel<<<dim3(E_ / 32, D_ / 32, H_), tb, 0, stream>>>(Wk, WkT, D_, E_);
    transpose_cast_kernel<<<dim3(E_ / 32, D_ / 32, H_), tb, 0, stream>>>(Wv, WvT, D_, E_);
    transpose_cast_kernel<<<dim3(E_ / 32, HE_ / 32, 1), tb, 0, stream>>>(Wo, WoT, HE_, E_);

    // 3) projections: Q,K -> [B,H,S,E]; V -> VT [B,H,E,S] via strided epilogue store
    gemm(Xq, WqT, bq, Qb, 0, S_, E_, D_, D_, D_,
         SD, 0, 0, ED, (long long)H_ * SE, SE, E_, 1, H_, E_, B_ * H_);
    gemm(Xk, WkT, bk, Kb, 0, S_, E_, D_, D_, D_,
         SD, 0, 0, ED, (long long)H_ * SE, SE, E_, 1, H_, E_, B_ * H_);
    gemm(Xv, WvT, bv, VT, 0, S_, E_, D_, D_, D_,
         SD, 0, 0, ED, (long long)H_ * ES, ES, 1, S_, H_, E_, B_ * H_);

    // 4) attention
    if (par) {
        // scores[z,s,t] fp16 (no scaling in reference!)
        gemm(Qb, Kb, nullptr, SC, 0, S_, S_, E_, E_, E_,
             0, SE, 0, SE, 0, SS, S_, 1, B_ * H_ /*divh: bb always 0*/ * 2, 0, B_ * H_);
        softmax_mask_kernel<<<dim3(S_, 1, B_ * H_), 256, 0, stream>>>(SC, mask, SS, H_, S_);
        // P @ V -> cat[b,s,h*E+e]
        gemm(SC, VT, nullptr, cat, 0, S_, E_, S_, S_, S_,
             (long long)H_ * SS, SS, (long long)H_ * ES, ES,
             (long long)S_ * HE_, E_, HE_, 1, H_, 0, B_ * H_);
    } else {
        for (int zz = 0; zz < B_ * H_; zz++) {
            gemm(Qb + (size_t)zz * SE, Kb + (size_t)zz * SE, nullptr, SC, 0,
                 S_, S_, E_, E_, E_, 0, 0, 0, 0, 0, 0, S_, 1, 1, 0, 1);
            softmax_mask_kernel<<<dim3(S_, 1, 1), 256, 0, stream>>>(
                SC, mask + (size_t)(zz / H_) * SS, 0, 1, S_);
            _Float16* Cz = cat + (size_t)(zz / H_) * S_ * HE_ + (size_t)(zz % H_) * E_;
            gemm(SC, VT + (size_t)zz * ES, nullptr, Cz, 0,
                 S_, E_, S_, S_, S_, 0, 0, 0, 0, 0, 0, HE_, 1, 1, 0, 1);
        }
    }

    // 5) output projection: cat[B*S, HE] @ WoT^T + bo -> fp32 d_out
    gemm(cat, WoT, bo, out, 1, B_ * S_, E_, HE_, HE_, HE_,
         0, 0, 0, 0, 0, 0, E_, 1, 1, 0, 1);
}

// Round 2
// 650.490 us; speedup vs baseline: 1.0855x; 1.0855x over previous
//
#include <hip/hip_runtime.h>

#define B_  2
#define S_  2048
#define D_  512
#define H_  8
#define E_  512
#define HE_ 4096

typedef _Float16 half8_t  __attribute__((ext_vector_type(8)));
typedef _Float16 half4_t  __attribute__((ext_vector_type(4)));
typedef float    floatx4  __attribute__((ext_vector_type(4)));
typedef __attribute__((address_space(1))) const unsigned int* gas_ptr;
typedef __attribute__((address_space(3))) unsigned int*       las_ptr;

// ---------------- cast fp32 -> fp16 (vectorized) ----------------
__global__ __launch_bounds__(256) void cast_f16_kernel(const float* __restrict__ src,
                                                       _Float16* __restrict__ dst, int n4) {
    int i = blockIdx.x * 256 + threadIdx.x;
    if (i >= n4) return;
    float4 v = ((const float4*)src)[i];
    half4_t h = { (_Float16)v.x, (_Float16)v.y, (_Float16)v.z, (_Float16)v.w };
    ((half4_t*)dst)[i] = h;
}

// ------------- transpose + cast: src fp32 [R,C] -> dst fp16 [C,R], batched -------------
__global__ __launch_bounds__(256) void transpose_cast_kernel(const float* __restrict__ src,
                                                             _Float16* __restrict__ dst,
                                                             int R, int C) {
    __shared__ float t[32][33];
    long long zoff = (long long)blockIdx.z * R * C;
    src += zoff; dst += zoff;
    int c0 = blockIdx.x * 32, r0 = blockIdx.y * 32;
    int tx = threadIdx.x, ty = threadIdx.y;
#pragma unroll
    for (int i = 0; i < 32; i += 8)
        t[ty + i][tx] = src[(long long)(r0 + ty + i) * C + (c0 + tx)];
    __syncthreads();
#pragma unroll
    for (int i = 0; i < 32; i += 8)
        dst[(long long)(c0 + ty + i) * R + (r0 + tx)] = (_Float16)t[tx][ty + i];
}

// ------------- bt-GEMM m97-style: C[M,N] = A[M,K] * Bt[N,K]^T (+bias[n]) -------------
// 128x128 tile, 256 threads = 4 waves in 2x2, each wave 64x64 (4x4 x 16x16x32 MFMA).
// Staging via global_load_lds width=16 (wave-uniform base + lane*16 -> LDS must be
// unpadded row-major [128][32]).
__global__ __launch_bounds__(256) void gemm_bt_kernel(
    const _Float16* __restrict__ A, const _Float16* __restrict__ Bt,
    const float* __restrict__ bias, void* __restrict__ C, int out_f32,
    int K, int lda, int ldb,
    long long a_b, long long a_h, long long b_b, long long b_h,
    long long c_b, long long c_h, int c_rs, int c_cs,
    int divh, int bias_h)
{
    int z  = blockIdx.z;
    int bb = z / divh, hh = z % divh;
    A  += bb * a_b + hh * a_h;
    Bt += bb * b_b + hh * b_h;
    long long coff = bb * c_b + hh * c_h;

    int m0 = blockIdx.y * 128;
    int n0 = blockIdx.x * 128;

    __shared__ __align__(16) _Float16 As[128][32];   // 8 KB, NO padding (global_load_lds)
    __shared__ __align__(16) _Float16 Bs[128][32];   // 8 KB

    int tid  = threadIdx.x;
    int wave = tid >> 6, lane = tid & 63;
    int quad = lane >> 4, l16 = lane & 15;
    int wy = (wave >> 1) * 64, wx = (wave & 1) * 64;

    // staging coords: call j covers rows [j*64, j*64+64); wave w rows [w*16, w*16+16)
    int srow = (wave << 4) + (lane >> 2);   // + j*64
    int scol = (lane & 3) * 8;
    _Float16* lA0 = &As[0][0] + (wave << 9);  // wave-uniform base (elements)
    _Float16* lB0 = &Bs[0][0] + (wave << 9);

    floatx4 acc[4][4] = {};

    for (int k0 = 0; k0 < K; k0 += 32) {
        if (k0) __syncthreads();
        const _Float16* gA = A + (long long)(m0 + srow) * lda + k0 + scol;
        const _Float16* gB = Bt + (long long)(n0 + srow) * ldb + k0 + scol;
#pragma unroll
        for (int j = 0; j < 2; j++) {
            __builtin_amdgcn_global_load_lds((gas_ptr)(gA + (long long)(j << 6) * lda),
                                             (las_ptr)(lA0 + (j << 11)), 16, 0, 0);
            __builtin_amdgcn_global_load_lds((gas_ptr)(gB + (long long)(j << 6) * ldb),
                                             (las_ptr)(lB0 + (j << 11)), 16, 0, 0);
        }
        __syncthreads();   // drains vmcnt -> LDS tiles ready

        half8_t af[4], bf[4];
#pragma unroll
        for (int i = 0; i < 4; i++) {
            af[i] = *(const half8_t*)&As[wy + i * 16 + l16][quad * 8];
            bf[i] = *(const half8_t*)&Bs[wx + i * 16 + l16][quad * 8];
        }
#pragma unroll
        for (int mi = 0; mi < 4; mi++)
#pragma unroll
            for (int ni = 0; ni < 4; ni++)
                acc[mi][ni] = __builtin_amdgcn_mfma_f32_16x16x32_f16(af[mi], bf[ni], acc[mi][ni], 0, 0, 0);
    }

    float*    fC = (float*)C;
    _Float16* hC = (_Float16*)C;
#pragma unroll
    for (int mi = 0; mi < 4; mi++)
#pragma unroll
        for (int ni = 0; ni < 4; ni++)
#pragma unroll
            for (int r = 0; r < 4; r++) {
                int row = m0 + wy + mi * 16 + quad * 4 + r;
                int col = n0 + wx + ni * 16 + l16;
                float v = acc[mi][ni][r];
                if (bias) v += bias[hh * bias_h + col];
                long long addr = coff + (long long)row * c_rs + (long long)col * c_cs;
                if (out_f32) fC[addr] = v; else hC[addr] = (_Float16)v;
            }
}

// ------------- masked softmax over one row of fp16 scores (in place) -------------
__global__ __launch_bounds__(256) void softmax_mask_kernel(_Float16* __restrict__ sc,
                                                           const int* __restrict__ mask,
                                                           long long sc_z, int hdiv, int S)
{
    long long z = blockIdx.z;
    int s = blockIdx.x;
    _Float16* row = sc + z * sc_z + (long long)s * S;
    const int* mrow = mask + (z / hdiv) * (long long)S * S + (long long)s * S;
    int tid = threadIdx.x;

    float v[8];
    float mx = -3.0e38f;
#pragma unroll
    for (int j = 0; j < 8; j++) {
        int c = tid + j * 256;
        float val = (float)row[c];
        val = mrow[c] ? val : -1.0e9f;
        v[j] = val;
        mx = fmaxf(mx, val);
    }
    __shared__ float red[4];
    for (int o = 32; o > 0; o >>= 1) mx = fmaxf(mx, __shfl_xor(mx, o));
    int wave = tid >> 6, lane = tid & 63;
    if (lane == 0) red[wave] = mx;
    __syncthreads();
    mx = fmaxf(fmaxf(red[0], red[1]), fmaxf(red[2], red[3]));

    float sum = 0.0f;
#pragma unroll
    for (int j = 0; j < 8; j++) { v[j] = __expf(v[j] - mx); sum += v[j]; }
    for (int o = 32; o > 0; o >>= 1) sum += __shfl_xor(sum, o);
    __syncthreads();
    if (lane == 0) red[wave] = sum;
    __syncthreads();
    sum = red[0] + red[1] + red[2] + red[3];
    float inv = 1.0f / sum;
#pragma unroll
    for (int j = 0; j < 8; j++) {
        int c = tid + j * 256;
        row[c] = (_Float16)(v[j] * inv);
    }
}

extern "C" void kernel_launch(void* const* d_in, const int* in_sizes, int n_in,
                              void* d_out, int out_size, void* d_ws, size_t ws_size,
                              hipStream_t stream)
{
    const float* qin = (const float*)d_in[0];
    const float* kin = (const float*)d_in[1];
    const float* vin = (const float*)d_in[2];
    const int*   mask = (const int*)d_in[3];
    const float* Wq = (const float*)d_in[4];
    const float* bq = (const float*)d_in[5];
    const float* Wk = (const float*)d_in[6];
    const float* bk = (const float*)d_in[7];
    const float* Wv = (const float*)d_in[8];
    const float* bv = (const float*)d_in[9];
    const float* Wo = (const float*)d_in[10];
    const float* bo = (const float*)d_in[11];
    float* out = (float*)d_out;

    char* ws = (char*)d_ws;
    size_t off = 0;
    _Float16* WoT = (_Float16*)(ws + off); off += (size_t)E_ * HE_ * 2;           // 4 MiB
    _Float16* Qb  = (_Float16*)(ws + off); off += (size_t)B_ * H_ * S_ * E_ * 2;  // 32 MiB
    _Float16* Kb  = (_Float16*)(ws + off); off += (size_t)B_ * H_ * S_ * E_ * 2;  // 32 MiB
    _Float16* VT  = (_Float16*)(ws + off); off += (size_t)B_ * H_ * E_ * S_ * 2;  // 32 MiB
    size_t region = off;
    _Float16* Xq  = (_Float16*)(ws + region);
    _Float16* Xk  = Xq  + (size_t)B_ * S_ * D_;
    _Float16* Xv  = Xk  + (size_t)B_ * S_ * D_;
    _Float16* WqT = Xv  + (size_t)B_ * S_ * D_;
    _Float16* WkT = WqT + (size_t)H_ * E_ * D_;
    _Float16* WvT = WkT + (size_t)H_ * E_ * D_;
    _Float16* SC  = (_Float16*)(ws + region);   // fp16 scores / P (in place)
    _Float16* cat = Qb;                          // aliases Q (dead after scores GEMM)

    size_t needPar = region + (size_t)B_ * H_ * S_ * S_ * 2;  // ~228 MiB
    int par = (ws_size >= needPar);

    long long SE = (long long)S_ * E_;
    long long SS = (long long)S_ * S_;
    long long ES = (long long)E_ * S_;
    long long SD = (long long)S_ * D_;
    long long ED = (long long)E_ * D_;

    auto gemm = [&](const _Float16* A, const _Float16* Bt, const float* bias,
                    void* C, int f32, int M, int N, int K, int lda, int ldb,
                    long long ab, long long ah, long long bb2, long long bh,
                    long long cb, long long ch, int rs, int cs,
                    int divh, int biash, int nz) {
        gemm_bt_kernel<<<dim3(N / 128, M / 128, nz), 256, 0, stream>>>(
            A, Bt, bias, C, f32, K, lda, ldb, ab, ah, bb2, bh, cb, ch, rs, cs, divh, biash);
    };

    // 1) cast inputs to fp16
    int n4 = B_ * S_ * D_ / 4;
    cast_f16_kernel<<<dim3(n4 / 256), 256, 0, stream>>>(qin, Xq, n4);
    cast_f16_kernel<<<dim3(n4 / 256), 256, 0, stream>>>(kin, Xk, n4);
    cast_f16_kernel<<<dim3(n4 / 256), 256, 0, stream>>>(vin, Xv, n4);

    // 2) transpose+cast weights to Bt form
    dim3 tb(32, 8);
    transpose_cast_kernel<<<dim3(E_ / 32, D_ / 32, H_), tb, 0, stream>>>(Wq, WqT, D_, E_);
    transpose_cast_kernel<<<dim3(E_ / 32, D_ / 32, H_), tb, 0, stream>>>(Wk, WkT, D_, E_);
    transpose_cast_kernel<<<dim3(E_ / 32, D_ / 32, H_), tb, 0, stream>>>(Wv, WvT, D_, E_);
    transpose_cast_kernel<<<dim3(E_ / 32, HE_ / 32, 1), tb, 0, stream>>>(Wo, WoT, HE_, E_);

    // 3) projections: Q,K -> [B,H,S,E]; V -> VT [B,H,E,S] via strided epilogue store
    gemm(Xq, WqT, bq, Qb, 0, S_, E_, D_, D_, D_,
         SD, 0, 0, ED, (long long)H_ * SE, SE, E_, 1, H_, E_, B_ * H_);
    gemm(Xk, WkT, bk, Kb, 0, S_, E_, D_, D_, D_,
         SD, 0, 0, ED, (long long)H_ * SE, SE, E_, 1, H_, E_, B_ * H_);
    gemm(Xv, WvT, bv, VT, 0, S_, E_, D_, D_, D_,
         SD, 0, 0, ED, (long long)H_ * ES, ES, 1, S_, H_, E_, B_ * H_);

    // 4) attention
    if (par) {
        gemm(Qb, Kb, nullptr, SC, 0, S_, S_, E_, E_, E_,
             0, SE, 0, SE, 0, SS, S_, 1, B_ * H_ * 2 /*divh>z: bb=0,hh=z*/, 0, B_ * H_);
        softmax_mask_kernel<<<dim3(S_, 1, B_ * H_), 256, 0, stream>>>(SC, mask, SS, H_, S_);
        gemm(SC, VT, nullptr, cat, 0, S_, E_, S_, S_, S_,
             (long long)H_ * SS, SS, (long long)H_ * ES, ES,
             (long long)S_ * HE_, E_, HE_, 1, H_, 0, B_ * H_);
    } else {
        for (int zz = 0; zz < B_ * H_; zz++) {
            gemm(Qb + (size_t)zz * SE, Kb + (size_t)zz * SE, nullptr, SC, 0,
                 S_, S_, E_, E_, E_, 0, 0, 0, 0, 0, 0, S_, 1, 1, 0, 1);
            softmax_mask_kernel<<<dim3(S_, 1, 1), 256, 0, stream>>>(
                SC, mask + (size_t)(zz / H_) * SS, 0, 1, S_);
            _Float16* Cz = cat + (size_t)(zz / H_) * S_ * HE_ + (size_t)(zz % H_) * E_;
            gemm(SC, VT + (size_t)zz * ES, nullptr, Cz, 0,
                 S_, E_, S_, S_, S_, 0, 0, 0, 0, 0, 0, HE_, 1, 1, 0, 1);
        }
    }

    // 5) output projection: cat[B*S, HE] @ WoT^T + bo -> fp32 d_out
    gemm(cat, WoT, bo, out, 1, B_ * S_, E_, HE_, HE_, HE_,
         0, 0, 0, 0, 0, 0, E_, 1, 1, 0, 1);
}

// Round 3
// 646.182 us; speedup vs baseline: 1.0928x; 1.0067x over previous
//
#include <hip/hip_runtime.h>

#define B_  2
#define S_  2048
#define D_  512
#define H_  8
#define E_  512
#define HE_ 4096

typedef _Float16 half8_t  __attribute__((ext_vector_type(8)));
typedef _Float16 half4_t  __attribute__((ext_vector_type(4)));
typedef float    floatx4  __attribute__((ext_vector_type(4)));
typedef __attribute__((address_space(1))) const unsigned int* gas_ptr;
typedef __attribute__((address_space(3))) unsigned int*       las_ptr;

// ---------------- cast fp32 -> fp16 (vectorized) ----------------
__global__ __launch_bounds__(256) void cast_f16_kernel(const float* __restrict__ src,
                                                       _Float16* __restrict__ dst, int n4) {
    int i = blockIdx.x * 256 + threadIdx.x;
    if (i >= n4) return;
    float4 v = ((const float4*)src)[i];
    half4_t h = { (_Float16)v.x, (_Float16)v.y, (_Float16)v.z, (_Float16)v.w };
    ((half4_t*)dst)[i] = h;
}

// ------------- transpose + cast: src fp32 [R,C] -> dst fp16 [C,R], batched -------------
__global__ __launch_bounds__(256) void transpose_cast_kernel(const float* __restrict__ src,
                                                             _Float16* __restrict__ dst,
                                                             int R, int C) {
    __shared__ float t[32][33];
    long long zoff = (long long)blockIdx.z * R * C;
    src += zoff; dst += zoff;
    int c0 = blockIdx.x * 32, r0 = blockIdx.y * 32;
    int tx = threadIdx.x, ty = threadIdx.y;
#pragma unroll
    for (int i = 0; i < 32; i += 8)
        t[ty + i][tx] = src[(long long)(r0 + ty + i) * C + (c0 + tx)];
    __syncthreads();
#pragma unroll
    for (int i = 0; i < 32; i += 8)
        dst[(long long)(c0 + ty + i) * R + (r0 + tx)] = (_Float16)t[tx][ty + i];
}

// ------------- bt-GEMM m97-style: C[M,N] = A[M,K] * Bt[N,K]^T (+bias[n]) -------------
// 128x128 tile, 256 threads = 4 waves in 2x2, each wave 64x64 (4x4 x 16x16x32 MFMA).
__global__ __launch_bounds__(256) void gemm_bt_kernel(
    const _Float16* __restrict__ A, const _Float16* __restrict__ Bt,
    const float* __restrict__ bias, void* __restrict__ C, int out_f32,
    int K, int lda, int ldb,
    long long a_b, long long a_h, long long b_b, long long b_h,
    long long c_b, long long c_h, int c_rs, int c_cs,
    int divh, int bias_h)
{
    int z  = blockIdx.z;
    int bb = z / divh, hh = z % divh;
    A  += bb * a_b + hh * a_h;
    Bt += bb * b_b + hh * b_h;
    long long coff = bb * c_b + hh * c_h;

    int m0 = blockIdx.y * 128;
    int n0 = blockIdx.x * 128;

    __shared__ __align__(16) _Float16 As[128][32];   // 8 KB, NO padding (global_load_lds)
    __shared__ __align__(16) _Float16 Bs[128][32];   // 8 KB

    int tid  = threadIdx.x;
    int wave = tid >> 6, lane = tid & 63;
    int quad = lane >> 4, l16 = lane & 15;
    int wy = (wave >> 1) * 64, wx = (wave & 1) * 64;

    int srow = (wave << 4) + (lane >> 2);
    int scol = (lane & 3) * 8;
    _Float16* lA0 = &As[0][0] + (wave << 9);
    _Float16* lB0 = &Bs[0][0] + (wave << 9);

    floatx4 acc[4][4] = {};

    for (int k0 = 0; k0 < K; k0 += 32) {
        if (k0) __syncthreads();
        const _Float16* gA = A + (long long)(m0 + srow) * lda + k0 + scol;
        const _Float16* gB = Bt + (long long)(n0 + srow) * ldb + k0 + scol;
#pragma unroll
        for (int j = 0; j < 2; j++) {
            __builtin_amdgcn_global_load_lds((gas_ptr)(gA + (long long)(j << 6) * lda),
                                             (las_ptr)(lA0 + (j << 11)), 16, 0, 0);
            __builtin_amdgcn_global_load_lds((gas_ptr)(gB + (long long)(j << 6) * ldb),
                                             (las_ptr)(lB0 + (j << 11)), 16, 0, 0);
        }
        __syncthreads();

        half8_t af[4], bf[4];
#pragma unroll
        for (int i = 0; i < 4; i++) {
            af[i] = *(const half8_t*)&As[wy + i * 16 + l16][quad * 8];
            bf[i] = *(const half8_t*)&Bs[wx + i * 16 + l16][quad * 8];
        }
#pragma unroll
        for (int mi = 0; mi < 4; mi++)
#pragma unroll
            for (int ni = 0; ni < 4; ni++)
                acc[mi][ni] = __builtin_amdgcn_mfma_f32_16x16x32_f16(af[mi], bf[ni], acc[mi][ni], 0, 0, 0);
    }

    float*    fC = (float*)C;
    _Float16* hC = (_Float16*)C;
#pragma unroll
    for (int mi = 0; mi < 4; mi++)
#pragma unroll
        for (int ni = 0; ni < 4; ni++)
#pragma unroll
            for (int r = 0; r < 4; r++) {
                int row = m0 + wy + mi * 16 + quad * 4 + r;
                int col = n0 + wx + ni * 16 + l16;
                float v = acc[mi][ni][r];
                if (bias) v += bias[hh * bias_h + col];
                long long addr = coff + (long long)row * c_rs + (long long)col * c_cs;
                if (out_f32) fC[addr] = v; else hC[addr] = (_Float16)v;
            }
}

// ------------- split-K bt-GEMM, 128(M)x64(N) tile, fp32 atomic accumulate -------------
// For the output projection: M=4096, N=512, K=4096 -> grid (8,32,ksplit) = 512 blocks.
// C must be zeroed before launch. bias added by the z==0 split.
__global__ __launch_bounds__(256) void gemm_bt_n64_splitk_kernel(
    const _Float16* __restrict__ A, const _Float16* __restrict__ Bt,
    const float* __restrict__ bias, float* __restrict__ C,
    int K, int lda, int ldb, int ldc, int ksplit)
{
    int m0 = blockIdx.y * 128;
    int n0 = blockIdx.x * 64;
    int kchunk = K / ksplit;
    int kbeg = blockIdx.z * kchunk;
    int kend = kbeg + kchunk;

    __shared__ __align__(16) _Float16 As[128][32];   // 8 KB
    __shared__ __align__(16) _Float16 Bs[64][32];    // 4 KB

    int tid  = threadIdx.x;
    int wave = tid >> 6, lane = tid & 63;
    int quad = lane >> 4, l16 = lane & 15;
    int wy = (wave >> 1) * 64, wx = (wave & 1) * 32;

    int srow = (wave << 4) + (lane >> 2);
    int scol = (lane & 3) * 8;
    _Float16* lA0 = &As[0][0] + (wave << 9);
    _Float16* lB0 = &Bs[0][0] + (wave << 9);

    floatx4 acc[4][2] = {};

    for (int k0 = kbeg; k0 < kend; k0 += 32) {
        if (k0 != kbeg) __syncthreads();
        const _Float16* gA = A + (long long)(m0 + srow) * lda + k0 + scol;
        const _Float16* gB = Bt + (long long)(n0 + srow) * ldb + k0 + scol;
#pragma unroll
        for (int j = 0; j < 2; j++)
            __builtin_amdgcn_global_load_lds((gas_ptr)(gA + (long long)(j << 6) * lda),
                                             (las_ptr)(lA0 + (j << 11)), 16, 0, 0);
        __builtin_amdgcn_global_load_lds((gas_ptr)gB, (las_ptr)lB0, 16, 0, 0);
        __syncthreads();

        half8_t af[4], bf[2];
#pragma unroll
        for (int i = 0; i < 4; i++)
            af[i] = *(const half8_t*)&As[wy + i * 16 + l16][quad * 8];
#pragma unroll
        for (int i = 0; i < 2; i++)
            bf[i] = *(const half8_t*)&Bs[wx + i * 16 + l16][quad * 8];
#pragma unroll
        for (int mi = 0; mi < 4; mi++)
#pragma unroll
            for (int ni = 0; ni < 2; ni++)
                acc[mi][ni] = __builtin_amdgcn_mfma_f32_16x16x32_f16(af[mi], bf[ni], acc[mi][ni], 0, 0, 0);
    }

    int addb = (blockIdx.z == 0) && bias;
#pragma unroll
    for (int mi = 0; mi < 4; mi++)
#pragma unroll
        for (int ni = 0; ni < 2; ni++)
#pragma unroll
            for (int r = 0; r < 4; r++) {
                int row = m0 + wy + mi * 16 + quad * 4 + r;
                int col = n0 + wx + ni * 16 + l16;
                float v = acc[mi][ni][r];
                if (addb) v += bias[col];
                atomicAdd(&C[(long long)row * ldc + col], v);
            }
}

// ------------- masked softmax over one row of fp16 scores (in place, vectorized) -------------
// grid: (S rows, 1, Z); block 256; thread t owns contiguous cols [t*8, t*8+8).
__global__ __launch_bounds__(256) void softmax_mask_kernel(_Float16* __restrict__ sc,
                                                           const int* __restrict__ mask,
                                                           long long sc_z, int hdiv, int S)
{
    long long z = blockIdx.z;
    int s = blockIdx.x;
    _Float16* row = sc + z * sc_z + (long long)s * S;
    const int* mrow = mask + (z / hdiv) * (long long)S * S + (long long)s * S;
    int tid = threadIdx.x;
    int c0 = tid * 8;

    half8_t h = *(const half8_t*)(row + c0);
    int4 mA = *(const int4*)(mrow + c0);
    int4 mB = *(const int4*)(mrow + c0 + 4);
    int m[8] = { mA.x, mA.y, mA.z, mA.w, mB.x, mB.y, mB.z, mB.w };

    float v[8];
    float mx = -3.0e38f;
#pragma unroll
    for (int j = 0; j < 8; j++) {
        float val = m[j] ? (float)h[j] : -1.0e9f;
        v[j] = val;
        mx = fmaxf(mx, val);
    }
    __shared__ float red[4];
    for (int o = 32; o > 0; o >>= 1) mx = fmaxf(mx, __shfl_xor(mx, o));
    int wave = tid >> 6, lane = tid & 63;
    if (lane == 0) red[wave] = mx;
    __syncthreads();
    mx = fmaxf(fmaxf(red[0], red[1]), fmaxf(red[2], red[3]));

    float sum = 0.0f;
#pragma unroll
    for (int j = 0; j < 8; j++) { v[j] = __expf(v[j] - mx); sum += v[j]; }
    for (int o = 32; o > 0; o >>= 1) sum += __shfl_xor(sum, o);
    __syncthreads();
    if (lane == 0) red[wave] = sum;
    __syncthreads();
    sum = red[0] + red[1] + red[2] + red[3];
    float inv = 1.0f / sum;
#pragma unroll
    for (int j = 0; j < 8; j++) h[j] = (_Float16)(v[j] * inv);
    *(half8_t*)(row + c0) = h;
}

extern "C" void kernel_launch(void* const* d_in, const int* in_sizes, int n_in,
                              void* d_out, int out_size, void* d_ws, size_t ws_size,
                              hipStream_t stream)
{
    const float* qin = (const float*)d_in[0];
    const float* kin = (const float*)d_in[1];
    const float* vin = (const float*)d_in[2];
    const int*   mask = (const int*)d_in[3];
    const float* Wq = (const float*)d_in[4];
    const float* bq = (const float*)d_in[5];
    const float* Wk = (const float*)d_in[6];
    const float* bk = (const float*)d_in[7];
    const float* Wv = (const float*)d_in[8];
    const float* bv = (const float*)d_in[9];
    const float* Wo = (const float*)d_in[10];
    const float* bo = (const float*)d_in[11];
    float* out = (float*)d_out;

    char* ws = (char*)d_ws;
    size_t off = 0;
    _Float16* WoT = (_Float16*)(ws + off); off += (size_t)E_ * HE_ * 2;           // 4 MiB
    _Float16* Qb  = (_Float16*)(ws + off); off += (size_t)B_ * H_ * S_ * E_ * 2;  // 32 MiB
    _Float16* Kb  = (_Float16*)(ws + off); off += (size_t)B_ * H_ * S_ * E_ * 2;  // 32 MiB
    _Float16* VT  = (_Float16*)(ws + off); off += (size_t)B_ * H_ * E_ * S_ * 2;  // 32 MiB
    size_t region = off;
    _Float16* Xq  = (_Float16*)(ws + region);
    _Float16* Xk  = Xq  + (size_t)B_ * S_ * D_;
    _Float16* Xv  = Xk  + (size_t)B_ * S_ * D_;
    _Float16* WqT = Xv  + (size_t)B_ * S_ * D_;
    _Float16* WkT = WqT + (size_t)H_ * E_ * D_;
    _Float16* WvT = WkT + (size_t)H_ * E_ * D_;
    _Float16* SC  = (_Float16*)(ws + region);   // fp16 scores / P (in place)
    _Float16* cat = Qb;                          // aliases Q (dead after scores GEMM)

    size_t needPar = region + (size_t)B_ * H_ * S_ * S_ * 2;  // ~228 MiB
    int par = (ws_size >= needPar);

    long long SE = (long long)S_ * E_;
    long long SS = (long long)S_ * S_;
    long long ES = (long long)E_ * S_;
    long long SD = (long long)S_ * D_;
    long long ED = (long long)E_ * D_;

    auto gemm = [&](const _Float16* A, const _Float16* Bt, const float* bias,
                    void* C, int f32, int M, int N, int K, int lda, int ldb,
                    long long ab, long long ah, long long bb2, long long bh,
                    long long cb, long long ch, int rs, int cs,
                    int divh, int biash, int nz) {
        gemm_bt_kernel<<<dim3(N / 128, M / 128, nz), 256, 0, stream>>>(
            A, Bt, bias, C, f32, K, lda, ldb, ab, ah, bb2, bh, cb, ch, rs, cs, divh, biash);
    };

    // zero d_out (split-K atomic accumulation target)
    hipMemsetAsync(d_out, 0, (size_t)out_size * sizeof(float), stream);

    // 1) cast inputs to fp16
    int n4 = B_ * S_ * D_ / 4;
    cast_f16_kernel<<<dim3(n4 / 256), 256, 0, stream>>>(qin, Xq, n4);
    cast_f16_kernel<<<dim3(n4 / 256), 256, 0, stream>>>(kin, Xk, n4);
    cast_f16_kernel<<<dim3(n4 / 256), 256, 0, stream>>>(vin, Xv, n4);

    // 2) transpose+cast weights to Bt form
    dim3 tb(32, 8);
    transpose_cast_kernel<<<dim3(E_ / 32, D_ / 32, H_), tb, 0, stream>>>(Wq, WqT, D_, E_);
    transpose_cast_kernel<<<dim3(E_ / 32, D_ / 32, H_), tb, 0, stream>>>(Wk, WkT, D_, E_);
    transpose_cast_kernel<<<dim3(E_ / 32, D_ / 32, H_), tb, 0, stream>>>(Wv, WvT, D_, E_);
    transpose_cast_kernel<<<dim3(E_ / 32, HE_ / 32, 1), tb, 0, stream>>>(Wo, WoT, HE_, E_);

    // 3) projections: Q,K -> [B,H,S,E]; V -> VT [B,H,E,S] via strided epilogue store
    gemm(Xq, WqT, bq, Qb, 0, S_, E_, D_, D_, D_,
         SD, 0, 0, ED, (long long)H_ * SE, SE, E_, 1, H_, E_, B_ * H_);
    gemm(Xk, WkT, bk, Kb, 0, S_, E_, D_, D_, D_,
         SD, 0, 0, ED, (long long)H_ * SE, SE, E_, 1, H_, E_, B_ * H_);
    gemm(Xv, WvT, bv, VT, 0, S_, E_, D_, D_, D_,
         SD, 0, 0, ED, (long long)H_ * ES, ES, 1, S_, H_, E_, B_ * H_);

    // 4) attention
    if (par) {
        gemm(Qb, Kb, nullptr, SC, 0, S_, S_, E_, E_, E_,
             0, SE, 0, SE, 0, SS, S_, 1, B_ * H_ * 2 /*divh>z: bb=0,hh=z*/, 0, B_ * H_);
        softmax_mask_kernel<<<dim3(S_, 1, B_ * H_), 256, 0, stream>>>(SC, mask, SS, H_, S_);
        gemm(SC, VT, nullptr, cat, 0, S_, E_, S_, S_, S_,
             (long long)H_ * SS, SS, (long long)H_ * ES, ES,
             (long long)S_ * HE_, E_, HE_, 1, H_, 0, B_ * H_);
    } else {
        for (int zz = 0; zz < B_ * H_; zz++) {
            gemm(Qb + (size_t)zz * SE, Kb + (size_t)zz * SE, nullptr, SC, 0,
                 S_, S_, E_, E_, E_, 0, 0, 0, 0, 0, 0, S_, 1, 1, 0, 1);
            softmax_mask_kernel<<<dim3(S_, 1, 1), 256, 0, stream>>>(
                SC, mask + (size_t)(zz / H_) * SS, 0, 1, S_);
            _Float16* Cz = cat + (size_t)(zz / H_) * S_ * HE_ + (size_t)(zz % H_) * E_;
            gemm(SC, VT + (size_t)zz * ES, nullptr, Cz, 0,
                 S_, E_, S_, S_, S_, 0, 0, 0, 0, 0, 0, HE_, 1, 1, 0, 1);
        }
    }

    // 5) output projection: split-K 128x64-tile GEMM, atomic fp32 accumulate
    //    grid (512/64, 4096/128, 2) = (8, 32, 2) = 512 blocks = 2 blocks/CU
    gemm_bt_n64_splitk_kernel<<<dim3(E_ / 64, (B_ * S_) / 128, 2), 256, 0, stream>>>(
        cat, WoT, bo, out, HE_, HE_, HE_, E_, 2);
}